// Round 4
// baseline (216.972 us; speedup 1.0000x reference)
//
#include <hip/hip_runtime.h>
#include <math.h>

// FourierKNOConv2d: x[8,32,256,256] f32, kernel[2,1,32,32,32,2] f32, r scalar.
// out[8,32,256,256] f32.
//   kP:  Kp = (kr + i ki)^r                                 [2,32,32,32] c64
//   kA:  Z1[row,w] = sum_x X[row,x] e^{-2pi i w x/256}, w<32 (x<->256-x symmetry)
//   kB1: in-place radix-8 over y2:  S[y1,p] = sum_{y2<8} z1[y1+32y2] e^{-2pi i p y2/8}
//        (stored at z1 row y1+32p; each thread owns its 8 cells -> race-free)
//   kB2: Z2[bc,t,w] = sum_{y1<32} S[y1, t&7, w] e^{-2pi i h(t) y1/256},
//        h(t)=t<32?t:192+t  (h&7 == t&7 since 192%8==0)
//   kC:  G = idft32_ch( dft32_ch(z2) * Kp ) / 8192
//   kD1: U[bc,y1,p,w] = sum_{t&7=p} G[bc,t,w] e^{+2pi i h(t) y1/256}
//   kDE: phase2: T[y,w] = sum_p U[y&31,p,w] e^{+2pi i p (y>>5)/8}  (8 iters)
//        phase3: out[row,x] = C(x)-S(x), out[row,256-x]=C(x)+S(x)  (x-symmetry)
// ws map (<= 24.5 MB, stream-ordered reuse):
//   z1/S @0..16M   (kA w, kB1 rw, kB2 r)
//   z2   @16..24M  (kB2 w, kC r)
//   kp   @24..24.5M (kP w, kC r)
//   g    @0..4M    (kC w, kD1 r; over dead z1)
//   U    @4..21M   (kD1 w, kDE r; over dead z1/S, z2 dead by then)

#define TWO_PI 6.28318530717958647692f

__global__ __launch_bounds__(256) void kP(const float* __restrict__ kin,
                                          const float* __restrict__ rp,
                                          float2* __restrict__ kp) {
  const int i = blockIdx.x * 256 + threadIdx.x;  // < 65536
  const float r = rp[0];
  const float kr = kin[2 * i], ki = kin[2 * i + 1];
  const float m2 = fmaf(kr, kr, ki * ki);
  float2 o = make_float2(0.f, 0.f);
  if (m2 > 0.f) {
    const float lm = 0.5f * logf(m2);
    const float ang = atan2f(ki, kr);
    const float mag = expf(r * lm);
    float s, c;
    sincosf(r * ang, &s, &c);
    o = make_float2(mag * c, mag * s);
  }
  kp[i] = o;
}

// kA: 2048 blocks; block = 32 rows. LDS 32 KB via rotate-swizzle:
//   word idx(x,r) = x*32 + ((r + 4x) & 31)
// (unchanged from R3 — measured best variant)
__global__ __launch_bounds__(256) void kA(const float* __restrict__ x,
                                          float2* __restrict__ z1) {
  __shared__ float xs[8192];  // 32 KB
  const int tid = threadIdx.x;
  const long row0 = (long)blockIdx.x * 32;
  const float* xg = x + row0 * 256;
  {
    const int xl = tid & 31, rq = tid >> 5;  // rows 4rq..4rq+3
    const float* xgr = xg + rq * 4 * 256 + xl;
#pragma unroll
    for (int cb = 0; cb < 8; ++cb) {
      const int xc = xl + 32 * cb;
      const float4 v = make_float4(xgr[32 * cb], xgr[32 * cb + 256],
                                   xgr[32 * cb + 512], xgr[32 * cb + 768]);
      *(float4*)(xs + xc * 32 + 4 * ((rq + xc) & 7)) = v;
    }
  }
  __syncthreads();
  for (int i = tid; i < 127 * 32; i += 256) {
    const int xi = 1 + (i >> 5), r = i & 31;
    const int ai = (xi << 5) + ((r + 4 * xi) & 31);
    const int bi = ((256 - xi) << 5) + ((r - 4 * xi) & 31);
    const float a = xs[ai], b = xs[bi];
    xs[ai] = a + b;          // u
    xs[bi] = a - b;          // v
  }
  __syncthreads();
  const int w = tid & 31;
  const int r0 = (tid >> 5) << 2;  // rows r0..r0+3
  int uo[8];                       // byte offsets of swizzled quad, period 8 in x
#pragma unroll
  for (int j = 0; j < 8; ++j) uo[j] = ((r0 + 4 * j) & 31) << 2;
  // edge terms: Re += X(0) + (-1)^w X(128)   (idx(0,r)=r, idx(128,r)=4096+r)
  const float sgn = (w & 1) ? -1.f : 1.f;
  const float4 x0 = *(const float4*)(xs + r0);
  const float4 x128 = *(const float4*)(xs + (128 << 5) + r0);
  float Cr0 = fmaf(sgn, x128.x, x0.x), Cr1 = fmaf(sgn, x128.y, x0.y);
  float Cr2 = fmaf(sgn, x128.z, x0.z), Cr3 = fmaf(sgn, x128.w, x0.w);
  float Ci0 = 0, Ci1 = 0, Ci2 = 0, Ci3 = 0;
  float s1, c1;
  sincosf(TWO_PI * (float)w / 256.0f, &s1, &c1);
  float pc = c1, ps = s1;  // phasor at x=1 (positive angle; sign applied on Im)
  const char* const xsb = (const char*)xs;
#define KA_BODY(UPTR, VPTR)                                        \
  {                                                                \
    const float4 u = *(const float4*)(UPTR);                       \
    const float4 v = *(const float4*)(VPTR);                       \
    Cr0 = fmaf(u.x, pc, Cr0); Ci0 = fmaf(-v.x, ps, Ci0);           \
    Cr1 = fmaf(u.y, pc, Cr1); Ci1 = fmaf(-v.y, ps, Ci1);           \
    Cr2 = fmaf(u.z, pc, Cr2); Ci2 = fmaf(-v.z, ps, Ci2);           \
    Cr3 = fmaf(u.w, pc, Cr3); Ci3 = fmaf(-v.w, ps, Ci3);           \
    const float tn = fmaf(pc, c1, -ps * s1);                       \
    ps = fmaf(pc, s1, ps * c1);                                    \
    pc = tn;                                                       \
  }
  {  // batch 0: xx = 1..7  (v at x'=256-j -> base 249*128 + (7-j)*128)
    const char* ub = xsb;
    const char* vb = xsb + 249 * 128;
#pragma unroll
    for (int j = 1; j < 8; ++j)
      KA_BODY(ub + j * 128 + uo[j], vb + (7 - j) * 128 + uo[8 - j])
  }
  for (int xb = 8; xb <= 120; xb += 8) {  // xx = 8..127
    const char* ub = xsb + xb * 128;
    const char* vb = xsb + (249 - xb) * 128;
#pragma unroll
    for (int j = 0; j < 8; ++j)
      KA_BODY(ub + j * 128 + uo[j], vb + (7 - j) * 128 + uo[(8 - j) & 7])
  }
#undef KA_BODY
  float2* o = z1 + (row0 + r0) * 32 + w;
  o[0]  = make_float2(Cr0, Ci0);
  o[32] = make_float2(Cr1, Ci1);
  o[64] = make_float2(Cr2, Ci2);
  o[96] = make_float2(Cr3, Ci3);
}

// kB1: in-place FFT-8 over y2. 1024 blocks x 256 thr = 1 thread per (bc,y1,w).
// Thread loads z1[bc][y1+32*y2][w] (y2<8), computes 8-pt complex DFT
// (negative exponent), stores S[p] back to row y1+32*p. Exclusive cell
// ownership -> race-free in-place. Loads/stores coalesced across w.
__global__ __launch_bounds__(256) void kB1(float2* __restrict__ z1) {
  const int gt = blockIdx.x * 256 + threadIdx.x;  // < 262144
  const int w = gt & 31, y1 = (gt >> 5) & 31, bc = gt >> 10;
  float2* base = z1 + (long)bc * 8192 + y1 * 32 + w;  // +j*1024 per y2-step
  float2 a[8];
#pragma unroll
  for (int j = 0; j < 8; ++j) a[j] = base[j * 1024];
  // DFT4 of evens (a0,a2,a4,a6)
  float2 t0 = make_float2(a[0].x + a[4].x, a[0].y + a[4].y);
  float2 t1 = make_float2(a[0].x - a[4].x, a[0].y - a[4].y);
  float2 t2 = make_float2(a[2].x + a[6].x, a[2].y + a[6].y);
  float2 t3 = make_float2(a[2].x - a[6].x, a[2].y - a[6].y);
  const float2 E0 = make_float2(t0.x + t2.x, t0.y + t2.y);
  const float2 E2 = make_float2(t0.x - t2.x, t0.y - t2.y);
  const float2 E1 = make_float2(t1.x + t3.y, t1.y - t3.x);  // t1 - i*t3
  const float2 E3 = make_float2(t1.x - t3.y, t1.y + t3.x);  // t1 + i*t3
  // DFT4 of odds (a1,a3,a5,a7)
  t0 = make_float2(a[1].x + a[5].x, a[1].y + a[5].y);
  t1 = make_float2(a[1].x - a[5].x, a[1].y - a[5].y);
  t2 = make_float2(a[3].x + a[7].x, a[3].y + a[7].y);
  t3 = make_float2(a[3].x - a[7].x, a[3].y - a[7].y);
  const float2 O0 = make_float2(t0.x + t2.x, t0.y + t2.y);
  const float2 O2 = make_float2(t0.x - t2.x, t0.y - t2.y);
  const float2 O1 = make_float2(t1.x + t3.y, t1.y - t3.x);
  const float2 O3 = make_float2(t1.x - t3.y, t1.y + t3.x);
  // twiddled odds: B_p = e^{-2pi i p/8} * O_p
  const float RT = 0.70710678118654752440f;
  const float2 B0 = O0;
  const float2 B1 = make_float2(RT * (O1.x + O1.y), RT * (O1.y - O1.x));
  const float2 B2 = make_float2(O2.y, -O2.x);                       // -i*O2
  const float2 B3 = make_float2(RT * (O3.y - O3.x), -RT * (O3.x + O3.y));
  base[0]        = make_float2(E0.x + B0.x, E0.y + B0.y);
  base[1 * 1024] = make_float2(E1.x + B1.x, E1.y + B1.y);
  base[2 * 1024] = make_float2(E2.x + B2.x, E2.y + B2.y);
  base[3 * 1024] = make_float2(E3.x + B3.x, E3.y + B3.y);
  base[4 * 1024] = make_float2(E0.x - B0.x, E0.y - B0.y);
  base[5 * 1024] = make_float2(E1.x - B1.x, E1.y - B1.y);
  base[6 * 1024] = make_float2(E2.x - B2.x, E2.y - B2.y);
  base[7 * 1024] = make_float2(E3.x - B3.x, E3.y - B3.y);
}

// kB2: 2048 blocks = (bc, tq). Thread = (k=tid>>5 -> t=tq*8+k, w=tid&31).
// Z2[t,w] = sum_{y1<32} S[y1, t&7, w] e^{-2pi i h y1/256}; t&7 == k.
// S row (y1,p) lives at z1 row y1+32p. 32-iter phasor loop, 1 output/thread.
__global__ __launch_bounds__(256) void kB2(const float2* __restrict__ s,
                                           float2* __restrict__ z2) {
  const int bc = blockIdx.x >> 3, tq = blockIdx.x & 7;
  const int k = threadIdx.x >> 5, w = threadIdx.x & 31;
  const int t = tq * 8 + k;
  const int h = (t < 32) ? t : (192 + t);
  float sr, cr;
  sincosf(-TWO_PI * (float)h / 256.0f, &sr, &cr);
  const float2* src = s + (long)bc * 8192 + k * 1024 + w;  // row y1+32k
  float ar = 0.f, ai = 0.f;
  float pc = 1.f, ps = 0.f;
  for (int y1 = 0; y1 < 32; ++y1) {
    const float2 v = src[y1 * 32];
    ar = fmaf(v.x, pc, fmaf(-v.y, ps, ar));
    ai = fmaf(v.x, ps, fmaf( v.y, pc, ai));
    const float tn = fmaf(pc, cr, -ps * sr);
    ps = fmaf(pc, sr, ps * cr);
    pc = tn;
  }
  z2[(long)bc * 2048 + t * 32 + w] = make_float2(ar, ai);
}

// kC: 1024 blocks; block = 16 modes (same b,t; 16 w). Single z2 input now.
__global__ __launch_bounds__(256) void kC(const float2* __restrict__ z2,
                                          const float2* __restrict__ kp,
                                          float2* __restrict__ g) {
  __shared__ float2 z2s[16 * 33];
  __shared__ float2 fk[16 * 33];
  __shared__ float2 tw[32];
  const int tid = threadIdx.x;
  if (tid < 32) {
    float s, c;
    sincosf(-TWO_PI * (float)tid / 32.0f, &s, &c);
    tw[tid] = make_float2(c, s);
  }
  const int m0 = blockIdx.x * 16;
  const int b = m0 >> 11;
  const int twi = m0 & 2047;
  const int t = twi >> 5;
  const int w0 = twi & 31;
  const int s_ = t >> 5, tm = t & 31;
  for (int i = tid; i < 512; i += 256) {
    const int ci = i >> 4, wj = i & 15;
    const long idx = ((long)(b * 32 + ci)) * 2048 + t * 32 + w0 + wj;
    z2s[wj * 33 + ci] = z2[idx];
  }
  __syncthreads();
  const int m = tid & 15;
  const int p = tid >> 4;
  const int cf0 = 2 * p, cf1 = 2 * p + 1;
  {
    float f0r = 0, f0i = 0, f1r = 0, f1i = 0;
    int i0 = 0, i1 = 0;
#pragma unroll 8
    for (int ci = 0; ci < 32; ++ci) {
      const float2 z = z2s[m * 33 + ci];
      const float2 t0 = tw[i0]; i0 = (i0 + cf0) & 31;
      const float2 t1 = tw[i1]; i1 = (i1 + cf1) & 31;
      f0r = fmaf(z.x, t0.x, fmaf(-z.y, t0.y, f0r));
      f0i = fmaf(z.x, t0.y, fmaf( z.y, t0.x, f0i));
      f1r = fmaf(z.x, t1.x, fmaf(-z.y, t1.y, f1r));
      f1i = fmaf(z.x, t1.y, fmaf( z.y, t1.x, f1i));
    }
    const float2 k0 = kp[((s_ * 32 + cf0) * 32 + tm) * 32 + w0 + m];
    const float2 k1 = kp[((s_ * 32 + cf1) * 32 + tm) * 32 + w0 + m];
    fk[m * 33 + cf0] = make_float2(f0r * k0.x - f0i * k0.y, f0r * k0.y + f0i * k0.x);
    fk[m * 33 + cf1] = make_float2(f1r * k1.x - f1i * k1.y, f1r * k1.y + f1i * k1.x);
  }
  __syncthreads();
  {
    float g0r = 0, g0i = 0, g1r = 0, g1i = 0;
    int i0 = 0, i1 = 0;
    const int co0 = 2 * p, co1 = 2 * p + 1;
#pragma unroll 8
    for (int cf = 0; cf < 32; ++cf) {
      const float2 f = fk[m * 33 + cf];
      const float2 t0 = tw[i0]; i0 = (i0 + co0) & 31;
      const float2 t1 = tw[i1]; i1 = (i1 + co1) & 31;
      g0r = fmaf(f.x, t0.x, fmaf( f.y, t0.y, g0r));
      g0i = fmaf(f.y, t0.x, fmaf(-f.x, t0.y, g0i));
      g1r = fmaf(f.x, t1.x, fmaf( f.y, t1.y, g1r));
      g1i = fmaf(f.y, t1.x, fmaf(-f.x, t1.y, g1i));
    }
    const float SC = 1.0f / 8192.0f;
    g[((long)(b * 32 + co0)) * 2048 + t * 32 + w0 + m] = make_float2(g0r * SC, g0i * SC);
    g[((long)(b * 32 + co1)) * 2048 + t * 32 + w0 + m] = make_float2(g1r * SC, g1i * SC);
  }
}

// kD1: U[bc,y1,p,w] = sum_{t&7=p} G[bc,t,w] e^{+2pi i h(t) y1/256}.
// t = p+8j (h=t) and t = 32+p+8j (h=224+p+8j), j<4. Both groups geometric in
// j with common step e^{+2pi i y1/32}; exact integer-mod start angles.
// 2048 blocks = (bc, y1q); thread = (p=tid>>5, w=tid&31), 4 y1 per thread.
__global__ __launch_bounds__(256) void kD1(const float2* __restrict__ g,
                                           float2* __restrict__ U) {
  const int bc = blockIdx.x >> 3, y1q = blockIdx.x & 7;
  const int p = threadIdx.x >> 5, w = threadIdx.x & 31;
  const float2* gb = g + (long)bc * 2048 + w;         // + t*32
  float2* ub = U + (long)bc * 8192 + p * 32 + w;      // + y1*256
#pragma unroll
  for (int y1l = 0; y1l < 4; ++y1l) {
    const int y1 = y1q * 4 + y1l;
    float st, ct;   // step e^{+2pi i y1/32}
    sincosf(TWO_PI * (float)y1 / 32.0f, &st, &ct);
    float s1, c1;   // start group1: e^{+2pi i p y1/256}
    sincosf(TWO_PI * (float)((p * y1) & 255) / 256.0f, &s1, &c1);
    float s2, c2;   // start group2: e^{+2pi i (224+p) y1/256}
    sincosf(TWO_PI * (float)(((224 + p) * y1) & 255) / 256.0f, &s2, &c2);
    float ar = 0.f, ai = 0.f;
    float pc = c1, ps = s1, qc = c2, qs = s2;
#pragma unroll
    for (int j = 0; j < 4; ++j) {
      const float2 va = gb[(p + 8 * j) * 32];
      const float2 vb = gb[(32 + p + 8 * j) * 32];
      ar = fmaf(va.x, pc, fmaf(-va.y, ps, ar));
      ai = fmaf(va.x, ps, fmaf( va.y, pc, ai));
      ar = fmaf(vb.x, qc, fmaf(-vb.y, qs, ar));
      ai = fmaf(vb.x, qs, fmaf( vb.y, qc, ai));
      const float tn = fmaf(pc, ct, -ps * st);
      ps = fmaf(pc, st, ps * ct);
      pc = tn;
      const float tm = fmaf(qc, ct, -qs * st);
      qs = fmaf(qc, st, qs * ct);
      qc = tm;
    }
    ub[y1 * 256] = make_float2(ar, ai);
  }
}

// kDE: 2048 blocks = (bc, yq); 32 rows/block.
// Phase 2: T[y5,w] = sum_{p<8} U[bc,y5,p,w] e^{+2pi i p yq/8} (8 iters, global
//   reads, exact integer-mod twiddles), scaled (1/256 w=0, 2/256 else) into
//   tst[w][y5] (stride 34 float2).
// Phase 3 (unchanged): thread = (xq=tid&31 -> x in {xq+32m}, rh=tid>>5 ->
//   rows 4rh..4rh+3); 4 x-phasors (steps related by x e^{i pi m/4}).
//   out(x)=C-S, out((256-x)&255)=C+S; col 128 via first-32-lane tail.
__global__ __launch_bounds__(256) void kDE(const float2* __restrict__ U,
                                           float* __restrict__ out) {
  __shared__ float2 tst[32 * 34]; // 8.5 KB
  const int tid = threadIdx.x;
  const int bc = blockIdx.x >> 3, yq = blockIdx.x & 7;
  {  // phase 2
    const int y5 = tid >> 3, wq = tid & 7;  // w = wq*4 + kk
    const float* ub = (const float*)(U + (long)bc * 8192 + (long)y5 * 256 + wq * 4);
    float Tr[4] = {0.f, 0.f, 0.f, 0.f}, Ti[4] = {0.f, 0.f, 0.f, 0.f};
#pragma unroll
    for (int p = 0; p < 8; ++p) {
      float sp, cp;
      sincosf(TWO_PI * (float)((p * yq) & 7) / 8.0f, &sp, &cp);
      const float4 qa = *(const float4*)(ub + p * 64);
      const float4 qb = *(const float4*)(ub + p * 64 + 4);
      Tr[0] = fmaf(qa.x, cp, fmaf(-qa.y, sp, Tr[0]));
      Ti[0] = fmaf(qa.x, sp, fmaf( qa.y, cp, Ti[0]));
      Tr[1] = fmaf(qa.z, cp, fmaf(-qa.w, sp, Tr[1]));
      Ti[1] = fmaf(qa.z, sp, fmaf( qa.w, cp, Ti[1]));
      Tr[2] = fmaf(qb.x, cp, fmaf(-qb.y, sp, Tr[2]));
      Ti[2] = fmaf(qb.x, sp, fmaf( qb.y, cp, Ti[2]));
      Tr[3] = fmaf(qb.z, cp, fmaf(-qb.w, sp, Tr[3]));
      Ti[3] = fmaf(qb.z, sp, fmaf( qb.w, cp, Ti[3]));
    }
#pragma unroll
    for (int kk = 0; kk < 4; ++kk) {
      const int w = wq * 4 + kk;
      const float sc = w ? (2.0f / 256.0f) : (1.0f / 256.0f);
      tst[w * 34 + y5] = make_float2(Tr[kk] * sc, Ti[kk] * sc);
    }
  }
  __syncthreads();
  {  // phase 3
    const int xq = tid & 31;  // x = xq + 32*m
    const int rh = tid >> 5;  // rows rh*4 .. rh*4+3
    float sb, cb;
    sincosf(TWO_PI * (float)xq / 256.0f, &sb, &cb);
    const float RT = 0.70710678118654752440f;
    const float stc1 = RT * (cb - sb), sts1 = RT * (cb + sb);
    const float stc[4] = {cb, stc1, -sb, -sts1};
    const float sts[4] = {sb, sts1, cb, stc1};
    float C[4][4], S[4][4];
#pragma unroll
    for (int m = 0; m < 4; ++m)
#pragma unroll
      for (int j = 0; j < 4; ++j) { C[m][j] = 0.f; S[m][j] = 0.f; }
    float pc[4] = {1.f, 1.f, 1.f, 1.f}, ps[4] = {0.f, 0.f, 0.f, 0.f};
    const float* tbse = (const float*)tst + rh * 8;
#pragma unroll 2
    for (int w = 0; w < 32; ++w) {
      const float4 q0 = *(const float4*)(tbse + w * 68);      // rows 4rh, 4rh+1
      const float4 q1 = *(const float4*)(tbse + w * 68 + 4);  // rows 4rh+2, 4rh+3
#pragma unroll
      for (int m = 0; m < 4; ++m) {
        C[m][0] = fmaf(q0.x, pc[m], C[m][0]);
        S[m][0] = fmaf(q0.y, ps[m], S[m][0]);
        C[m][1] = fmaf(q0.z, pc[m], C[m][1]);
        S[m][1] = fmaf(q0.w, ps[m], S[m][1]);
        C[m][2] = fmaf(q1.x, pc[m], C[m][2]);
        S[m][2] = fmaf(q1.y, ps[m], S[m][2]);
        C[m][3] = fmaf(q1.z, pc[m], C[m][3]);
        S[m][3] = fmaf(q1.w, ps[m], S[m][3]);
        const float tn = fmaf(pc[m], stc[m], -ps[m] * sts[m]);
        ps[m] = fmaf(pc[m], sts[m], ps[m] * stc[m]);
        pc[m] = tn;
      }
    }
    const long rbase = (long)bc * 256 + yq * 32;
#pragma unroll
    for (int m = 0; m < 4; ++m) {
      const int xx = xq + 32 * m;
#pragma unroll
      for (int j = 0; j < 4; ++j) {
        const long row = rbase + rh * 4 + j;
        out[row * 256 + xx] = C[m][j] - S[m][j];
        out[row * 256 + ((256 - xx) & 255)] = C[m][j] + S[m][j];
      }
    }
    if (tid < 32) {  // column x=128: sum (-1)^w a_w
      float ae = 0.f, ao = 0.f;
#pragma unroll
      for (int k = 0; k < 16; ++k) {
        ae += tst[(2 * k) * 34 + tid].x;
        ao += tst[(2 * k + 1) * 34 + tid].x;
      }
      out[(rbase + tid) * 256 + 128] = ae - ao;
    }
  }
}

extern "C" void kernel_launch(void* const* d_in, const int* in_sizes, int n_in,
                              void* d_out, int out_size, void* d_ws, size_t ws_size,
                              hipStream_t stream) {
  const float* x = (const float*)d_in[0];
  const float* kin = (const float*)d_in[1];
  const float* rp = (const float*)d_in[2];
  float* out = (float*)d_out;
  char* ws = (char*)d_ws;

  float2* z1 = (float2*)(ws);                   // 0..16M (kA w, kB1 rw, kB2 r)
  float2* z2 = (float2*)(ws + (16ull << 20));   // 16..24M (kB2 w, kC r)
  float2* kp = (float2*)(ws + (24ull << 20));   // 24..24.5M (kP w, kC r)
  float2* g  = (float2*)(ws);                   // 0..4M (kC w, kD1 r)
  float2* U  = (float2*)(ws + (4ull << 20));    // 4..21M (kD1 w, kDE r)

  kP<<<256, 256, 0, stream>>>(kin, rp, kp);
  kA<<<2048, 256, 0, stream>>>(x, z1);
  kB1<<<1024, 256, 0, stream>>>(z1);
  kB2<<<2048, 256, 0, stream>>>(z1, z2);
  kC<<<1024, 256, 0, stream>>>(z2, kp, g);
  kD1<<<2048, 256, 0, stream>>>(g, U);
  kDE<<<2048, 256, 0, stream>>>(U, out);
}

// Round 5
// 202.860 us; speedup vs baseline: 1.0696x; 1.0696x over previous
//
#include <hip/hip_runtime.h>
#include <math.h>

// FourierKNOConv2d: x[8,32,256,256] f32, kernel[2,1,32,32,32,2] f32, r scalar.
// out[8,32,256,256] f32.
//   kP:  Kp = (kr + i ki)^r                                 [2,32,32,32] c64
//   kA:  Z1[row,w] = sum_x X[row,x] e^{-2pi i w x/256}, w<32
//        via x = x1+32*x2: in-LDS real FFT8 over x2, then 32-term phasor sum.
//   kB1: in-place radix-8 over y2:  S[y1,p] = sum_{y2<8} z1[y1+32y2] e^{-2pi i p y2/8}
//   kB2: Z2[bc,t,w] = sum_{y1<32} S[y1, t&7, w] e^{-2pi i h(t) y1/256},
//        h(t)=t<32?t:192+t
//   kC:  G = idft32_ch( dft32_ch(z2) * Kp ) / 8192   (8-mode blocks)
//   kD1: U[bc,y1,p,w] = sum_{t&7=p} G[bc,t,w] e^{+2pi i h(t) y1/256}
//   kDE: phase2: T[y,w] = sum_p U[y&31,p,w] e^{+2pi i p (y>>5)/8}  (8 iters)
//        phase3: out[row,x] = C(x)-S(x), out[row,256-x]=C(x)+S(x)  (x-symmetry)
// ws map (<= 24.5 MB, stream-ordered reuse):
//   z1/S @0..16M   (kA w, kB1 rw, kB2 r)
//   z2   @16..24M  (kB2 w, kC r)
//   kp   @24..24.5M (kP w, kC r)
//   g    @0..4M    (kC w, kD1 r; over dead z1)
//   U    @4..21M   (kD1 w, kDE r; over dead z1/S, z2 dead by then)

#define TWO_PI 6.28318530717958647692f

__global__ __launch_bounds__(256) void kP(const float* __restrict__ kin,
                                          const float* __restrict__ rp,
                                          float2* __restrict__ kp) {
  const int i = blockIdx.x * 256 + threadIdx.x;  // < 65536
  const float r = rp[0];
  const float kr = kin[2 * i], ki = kin[2 * i + 1];
  const float m2 = fmaf(kr, kr, ki * ki);
  float2 o = make_float2(0.f, 0.f);
  if (m2 > 0.f) {
    const float lm = 0.5f * logf(m2);
    const float ang = atan2f(ki, kr);
    const float mag = expf(r * lm);
    float s, c;
    sincosf(r * ang, &s, &c);
    o = make_float2(mag * c, mag * s);
  }
  kp[i] = o;
}

// kA: 2048 blocks; block = 32 rows. LDS 32 KB, rotate-swizzle
//   word idx(x,r) = x*32 + ((r + 4x) & 31)   (rotation indep. of x2=x>>5 part)
// Pass1: stage X (b128 quads, as R3/R4).
// Pass2: per (x1<32, r<32): real FFT8 over x2 (8 cells stride 1024 words, one
//   bank per lane-mapping (x1=i>>5, r=i&31) -> conflict-free). In-place
//   component layout in x2-slots: [F0, F4, F1r, F1i, F2r, F2i, F3r, F3i]
//   (F_{8-p} = conj(F_p) since X real).
// Pass3: thread = (w=tid&31, rq=tid>>5 -> rows 4rq..+3):
//   Z1[w] = sum_{x1<32} F[x1, w&7] e^{-2pi i w x1/256}.
//   p=w&7 -> component slots (pr,pi) + conj sign si; 8 precomputed LDS base
//   pointers (swizzle offset + 128j folded in) -> zero addr VALU in loop;
//   per iter: 2 ds_read_b128 + 16 FMA + 2 mul + 4 phasor.
__global__ __launch_bounds__(256) void kA(const float* __restrict__ x,
                                          float2* __restrict__ z1) {
  __shared__ float xs[8192];  // 32 KB
  const int tid = threadIdx.x;
  const long row0 = (long)blockIdx.x * 32;
  const float* xg = x + row0 * 256;
  {
    const int xl = tid & 31, rq = tid >> 5;  // rows 4rq..4rq+3
    const float* xgr = xg + rq * 4 * 256 + xl;
#pragma unroll
    for (int cb = 0; cb < 8; ++cb) {
      const int xc = xl + 32 * cb;
      const float4 v = make_float4(xgr[32 * cb], xgr[32 * cb + 256],
                                   xgr[32 * cb + 512], xgr[32 * cb + 768]);
      *(float4*)(xs + xc * 32 + 4 * ((rq + xc) & 7)) = v;
    }
  }
  __syncthreads();
  // pass2: real FFT8 over x2, in place. Thread owns 4 (x1,r) pairs.
  const float RT = 0.70710678118654752440f;
#pragma unroll
  for (int k = 0; k < 4; ++k) {
    const int i = tid + (k << 8);
    const int x1 = i >> 5, r = i & 31;
    float* base = xs + x1 * 32 + ((r + 4 * x1) & 31);  // +1024 per x2
    const float a0 = base[0],        a1 = base[1024],     a2 = base[2048];
    const float a3 = base[3 * 1024], a4 = base[4 * 1024], a5 = base[5 * 1024];
    const float a6 = base[6 * 1024], a7 = base[7 * 1024];
    const float t0 = a0 + a4, t1 = a0 - a4, t2 = a2 + a6, t3 = a2 - a6;
    const float u0 = a1 + a5, u1 = a1 - a5, u2 = a3 + a7, u3 = a3 - a7;
    const float E0 = t0 + t2, O0 = u0 + u2;
    const float d1 = RT * (u1 - u3), d2 = RT * (u1 + u3);
    base[0]        = E0 + O0;            // F0
    base[1024]     = E0 - O0;            // F4
    base[2 * 1024] = t1 + d1;            // F1r
    base[3 * 1024] = -(t3 + d2);         // F1i
    base[4 * 1024] = t0 - t2;            // F2r
    base[5 * 1024] = -(u0 - u2);         // F2i
    base[6 * 1024] = t1 - d1;            // F3r
    base[7 * 1024] = t3 - d2;            // F3i
  }
  __syncthreads();
  // pass3
  const int w = tid & 31;
  const int r0 = (tid >> 5) << 2;  // rows r0..r0+3
  const int p = w & 7;
  int pr, pi;
  float si;
  if (p == 0)      { pr = 0;           pi = 0;      si = 0.f; }
  else if (p == 4) { pr = 1;           pi = 1;      si = 0.f; }
  else if (p < 4)  { pr = 2 * p;       pi = pr + 1; si = 1.f; }
  else             { pr = 2 * (8 - p); pi = pr + 1; si = -1.f; }
  const char* ur = (const char*)xs + pr * 4096;
  const char* ui = (const char*)xs + pi * 4096;
  const char* urp[8];
  const char* uip[8];
#pragma unroll
  for (int j = 0; j < 8; ++j) {
    const int off = 4 * ((r0 + 4 * j) & 31) + 128 * j;
    urp[j] = ur + off;
    uip[j] = ui + off;
  }
  float s1, c1;
  sincosf(-TWO_PI * (float)w / 256.0f, &s1, &c1);
  float pc = 1.f, ps = 0.f;
  float Cr0 = 0, Cr1 = 0, Cr2 = 0, Cr3 = 0;
  float Ci0 = 0, Ci1 = 0, Ci2 = 0, Ci3 = 0;
#pragma unroll
  for (int bq = 0; bq < 4; ++bq) {
#pragma unroll
    for (int j = 0; j < 8; ++j) {
      const float4 Fr = *(const float4*)(urp[j] + bq * 1024);
      const float4 Fi = *(const float4*)(uip[j] + bq * 1024);
      const float qs = si * ps, qc = si * pc;
      Cr0 = fmaf(Fr.x, pc, fmaf(-Fi.x, qs, Cr0));
      Ci0 = fmaf(Fr.x, ps, fmaf( Fi.x, qc, Ci0));
      Cr1 = fmaf(Fr.y, pc, fmaf(-Fi.y, qs, Cr1));
      Ci1 = fmaf(Fr.y, ps, fmaf( Fi.y, qc, Ci1));
      Cr2 = fmaf(Fr.z, pc, fmaf(-Fi.z, qs, Cr2));
      Ci2 = fmaf(Fr.z, ps, fmaf( Fi.z, qc, Ci2));
      Cr3 = fmaf(Fr.w, pc, fmaf(-Fi.w, qs, Cr3));
      Ci3 = fmaf(Fr.w, ps, fmaf( Fi.w, qc, Ci3));
      const float tn = fmaf(pc, c1, -ps * s1);
      ps = fmaf(pc, s1, ps * c1);
      pc = tn;
    }
  }
  float2* o = z1 + (row0 + r0) * 32 + w;
  o[0]  = make_float2(Cr0, Ci0);
  o[32] = make_float2(Cr1, Ci1);
  o[64] = make_float2(Cr2, Ci2);
  o[96] = make_float2(Cr3, Ci3);
}

// kB1: in-place FFT-8 over y2. 1024 blocks x 256 thr = 1 thread per (bc,y1,w).
__global__ __launch_bounds__(256) void kB1(float2* __restrict__ z1) {
  const int gt = blockIdx.x * 256 + threadIdx.x;  // < 262144
  const int w = gt & 31, y1 = (gt >> 5) & 31, bc = gt >> 10;
  float2* base = z1 + (long)bc * 8192 + y1 * 32 + w;  // +j*1024 per y2-step
  float2 a[8];
#pragma unroll
  for (int j = 0; j < 8; ++j) a[j] = base[j * 1024];
  float2 t0 = make_float2(a[0].x + a[4].x, a[0].y + a[4].y);
  float2 t1 = make_float2(a[0].x - a[4].x, a[0].y - a[4].y);
  float2 t2 = make_float2(a[2].x + a[6].x, a[2].y + a[6].y);
  float2 t3 = make_float2(a[2].x - a[6].x, a[2].y - a[6].y);
  const float2 E0 = make_float2(t0.x + t2.x, t0.y + t2.y);
  const float2 E2 = make_float2(t0.x - t2.x, t0.y - t2.y);
  const float2 E1 = make_float2(t1.x + t3.y, t1.y - t3.x);  // t1 - i*t3
  const float2 E3 = make_float2(t1.x - t3.y, t1.y + t3.x);  // t1 + i*t3
  t0 = make_float2(a[1].x + a[5].x, a[1].y + a[5].y);
  t1 = make_float2(a[1].x - a[5].x, a[1].y - a[5].y);
  t2 = make_float2(a[3].x + a[7].x, a[3].y + a[7].y);
  t3 = make_float2(a[3].x - a[7].x, a[3].y - a[7].y);
  const float2 O0 = make_float2(t0.x + t2.x, t0.y + t2.y);
  const float2 O2 = make_float2(t0.x - t2.x, t0.y - t2.y);
  const float2 O1 = make_float2(t1.x + t3.y, t1.y - t3.x);
  const float2 O3 = make_float2(t1.x - t3.y, t1.y + t3.x);
  const float RT = 0.70710678118654752440f;
  const float2 B0 = O0;
  const float2 B1 = make_float2(RT * (O1.x + O1.y), RT * (O1.y - O1.x));
  const float2 B2 = make_float2(O2.y, -O2.x);  // -i*O2
  const float2 B3 = make_float2(RT * (O3.y - O3.x), -RT * (O3.x + O3.y));
  base[0]        = make_float2(E0.x + B0.x, E0.y + B0.y);
  base[1 * 1024] = make_float2(E1.x + B1.x, E1.y + B1.y);
  base[2 * 1024] = make_float2(E2.x + B2.x, E2.y + B2.y);
  base[3 * 1024] = make_float2(E3.x + B3.x, E3.y + B3.y);
  base[4 * 1024] = make_float2(E0.x - B0.x, E0.y - B0.y);
  base[5 * 1024] = make_float2(E1.x - B1.x, E1.y - B1.y);
  base[6 * 1024] = make_float2(E2.x - B2.x, E2.y - B2.y);
  base[7 * 1024] = make_float2(E3.x - B3.x, E3.y - B3.y);
}

// kB2: 2048 blocks = (bc, tq). Thread = (k=tid>>5 -> t=tq*8+k, w=tid&31).
__global__ __launch_bounds__(256) void kB2(const float2* __restrict__ s,
                                           float2* __restrict__ z2) {
  const int bc = blockIdx.x >> 3, tq = blockIdx.x & 7;
  const int k = threadIdx.x >> 5, w = threadIdx.x & 31;
  const int t = tq * 8 + k;
  const int h = (t < 32) ? t : (192 + t);
  float sr, cr;
  sincosf(-TWO_PI * (float)h / 256.0f, &sr, &cr);
  const float2* src = s + (long)bc * 8192 + k * 1024 + w;  // row y1+32k
  float ar = 0.f, ai = 0.f;
  float pc = 1.f, ps = 0.f;
  for (int y1 = 0; y1 < 32; ++y1) {
    const float2 v = src[y1 * 32];
    ar = fmaf(v.x, pc, fmaf(-v.y, ps, ar));
    ai = fmaf(v.x, ps, fmaf( v.y, pc, ai));
    const float tn = fmaf(pc, cr, -ps * sr);
    ps = fmaf(pc, sr, ps * cr);
    pc = tn;
  }
  z2[(long)bc * 2048 + t * 32 + w] = make_float2(ar, ai);
}

// kC: 2048 blocks; block = 8 modes (same b,t; 8 w). 1 output/thread/pass,
// ~4.3 KB LDS -> high blocks/CU (tests the latency/ramp theory mid-pipeline).
__global__ __launch_bounds__(256) void kC(const float2* __restrict__ z2,
                                          const float2* __restrict__ kp,
                                          float2* __restrict__ g) {
  __shared__ float2 z2s[8 * 33];
  __shared__ float2 fk[8 * 33];
  __shared__ float2 tw[32];
  const int tid = threadIdx.x;
  if (tid < 32) {
    float s, c;
    sincosf(-TWO_PI * (float)tid / 32.0f, &s, &c);
    tw[tid] = make_float2(c, s);
  }
  const int m0 = blockIdx.x * 8;
  const int b = m0 >> 11;
  const int twi = m0 & 2047;
  const int t = twi >> 5;
  const int w0 = twi & 31;
  const int s_ = t >> 5, tm = t & 31;
  {
    const int ci = tid >> 3, wj = tid & 7;
    z2s[wj * 33 + ci] = z2[((long)(b * 32 + ci)) * 2048 + t * 32 + w0 + wj];
  }
  __syncthreads();
  const int m = tid & 7;
  {
    const int cf = tid >> 3;
    float fr = 0, fi = 0;
    int i0 = 0;
#pragma unroll 8
    for (int ci = 0; ci < 32; ++ci) {
      const float2 z = z2s[m * 33 + ci];
      const float2 t0 = tw[i0]; i0 = (i0 + cf) & 31;
      fr = fmaf(z.x, t0.x, fmaf(-z.y, t0.y, fr));
      fi = fmaf(z.x, t0.y, fmaf( z.y, t0.x, fi));
    }
    const float2 k0 = kp[((s_ * 32 + cf) * 32 + tm) * 32 + w0 + m];
    fk[m * 33 + cf] = make_float2(fr * k0.x - fi * k0.y, fr * k0.y + fi * k0.x);
  }
  __syncthreads();
  {
    const int co = tid >> 3;
    float gr = 0, gi = 0;
    int i0 = 0;
#pragma unroll 8
    for (int cf = 0; cf < 32; ++cf) {
      const float2 f = fk[m * 33 + cf];
      const float2 t0 = tw[i0]; i0 = (i0 + co) & 31;
      gr = fmaf(f.x, t0.x, fmaf( f.y, t0.y, gr));
      gi = fmaf(f.y, t0.x, fmaf(-f.x, t0.y, gi));
    }
    const float SC = 1.0f / 8192.0f;
    g[((long)(b * 32 + co)) * 2048 + t * 32 + w0 + m] = make_float2(gr * SC, gi * SC);
  }
}

// kD1: U[bc,y1,p,w] = sum_{t&7=p} G[bc,t,w] e^{+2pi i h(t) y1/256}.
__global__ __launch_bounds__(256) void kD1(const float2* __restrict__ g,
                                           float2* __restrict__ U) {
  const int bc = blockIdx.x >> 3, y1q = blockIdx.x & 7;
  const int p = threadIdx.x >> 5, w = threadIdx.x & 31;
  const float2* gb = g + (long)bc * 2048 + w;         // + t*32
  float2* ub = U + (long)bc * 8192 + p * 32 + w;      // + y1*256
#pragma unroll
  for (int y1l = 0; y1l < 4; ++y1l) {
    const int y1 = y1q * 4 + y1l;
    float st, ct;   // step e^{+2pi i y1/32}
    sincosf(TWO_PI * (float)y1 / 32.0f, &st, &ct);
    float s1, c1;   // start group1: e^{+2pi i p y1/256}
    sincosf(TWO_PI * (float)((p * y1) & 255) / 256.0f, &s1, &c1);
    float s2, c2;   // start group2: e^{+2pi i (224+p) y1/256}
    sincosf(TWO_PI * (float)(((224 + p) * y1) & 255) / 256.0f, &s2, &c2);
    float ar = 0.f, ai = 0.f;
    float pc = c1, ps = s1, qc = c2, qs = s2;
#pragma unroll
    for (int j = 0; j < 4; ++j) {
      const float2 va = gb[(p + 8 * j) * 32];
      const float2 vb = gb[(32 + p + 8 * j) * 32];
      ar = fmaf(va.x, pc, fmaf(-va.y, ps, ar));
      ai = fmaf(va.x, ps, fmaf( va.y, pc, ai));
      ar = fmaf(vb.x, qc, fmaf(-vb.y, qs, ar));
      ai = fmaf(vb.x, qs, fmaf( vb.y, qc, ai));
      const float tn = fmaf(pc, ct, -ps * st);
      ps = fmaf(pc, st, ps * ct);
      pc = tn;
      const float tm2 = fmaf(qc, ct, -qs * st);
      qs = fmaf(qc, st, qs * ct);
      qc = tm2;
    }
    ub[y1 * 256] = make_float2(ar, ai);
  }
}

// kDE: 2048 blocks = (bc, yq); 32 rows/block. (unchanged from R4)
__global__ __launch_bounds__(256) void kDE(const float2* __restrict__ U,
                                           float* __restrict__ out) {
  __shared__ float2 tst[32 * 34]; // 8.5 KB
  const int tid = threadIdx.x;
  const int bc = blockIdx.x >> 3, yq = blockIdx.x & 7;
  {  // phase 2
    const int y5 = tid >> 3, wq = tid & 7;  // w = wq*4 + kk
    const float* ub = (const float*)(U + (long)bc * 8192 + (long)y5 * 256 + wq * 4);
    float Tr[4] = {0.f, 0.f, 0.f, 0.f}, Ti[4] = {0.f, 0.f, 0.f, 0.f};
#pragma unroll
    for (int p = 0; p < 8; ++p) {
      float sp, cp;
      sincosf(TWO_PI * (float)((p * yq) & 7) / 8.0f, &sp, &cp);
      const float4 qa = *(const float4*)(ub + p * 64);
      const float4 qb = *(const float4*)(ub + p * 64 + 4);
      Tr[0] = fmaf(qa.x, cp, fmaf(-qa.y, sp, Tr[0]));
      Ti[0] = fmaf(qa.x, sp, fmaf( qa.y, cp, Ti[0]));
      Tr[1] = fmaf(qa.z, cp, fmaf(-qa.w, sp, Tr[1]));
      Ti[1] = fmaf(qa.z, sp, fmaf( qa.w, cp, Ti[1]));
      Tr[2] = fmaf(qb.x, cp, fmaf(-qb.y, sp, Tr[2]));
      Ti[2] = fmaf(qb.x, sp, fmaf( qb.y, cp, Ti[2]));
      Tr[3] = fmaf(qb.z, cp, fmaf(-qb.w, sp, Tr[3]));
      Ti[3] = fmaf(qb.z, sp, fmaf( qb.w, cp, Ti[3]));
    }
#pragma unroll
    for (int kk = 0; kk < 4; ++kk) {
      const int w = wq * 4 + kk;
      const float sc = w ? (2.0f / 256.0f) : (1.0f / 256.0f);
      tst[w * 34 + y5] = make_float2(Tr[kk] * sc, Ti[kk] * sc);
    }
  }
  __syncthreads();
  {  // phase 3
    const int xq = tid & 31;  // x = xq + 32*m
    const int rh = tid >> 5;  // rows rh*4 .. rh*4+3
    float sb, cb;
    sincosf(TWO_PI * (float)xq / 256.0f, &sb, &cb);
    const float RT = 0.70710678118654752440f;
    const float stc1 = RT * (cb - sb), sts1 = RT * (cb + sb);
    const float stc[4] = {cb, stc1, -sb, -sts1};
    const float sts[4] = {sb, sts1, cb, stc1};
    float C[4][4], S[4][4];
#pragma unroll
    for (int m = 0; m < 4; ++m)
#pragma unroll
      for (int j = 0; j < 4; ++j) { C[m][j] = 0.f; S[m][j] = 0.f; }
    float pc[4] = {1.f, 1.f, 1.f, 1.f}, ps[4] = {0.f, 0.f, 0.f, 0.f};
    const float* tbse = (const float*)tst + rh * 8;
#pragma unroll 2
    for (int w = 0; w < 32; ++w) {
      const float4 q0 = *(const float4*)(tbse + w * 68);      // rows 4rh, 4rh+1
      const float4 q1 = *(const float4*)(tbse + w * 68 + 4);  // rows 4rh+2, 4rh+3
#pragma unroll
      for (int m = 0; m < 4; ++m) {
        C[m][0] = fmaf(q0.x, pc[m], C[m][0]);
        S[m][0] = fmaf(q0.y, ps[m], S[m][0]);
        C[m][1] = fmaf(q0.z, pc[m], C[m][1]);
        S[m][1] = fmaf(q0.w, ps[m], S[m][1]);
        C[m][2] = fmaf(q1.x, pc[m], C[m][2]);
        S[m][2] = fmaf(q1.y, ps[m], S[m][2]);
        C[m][3] = fmaf(q1.z, pc[m], C[m][3]);
        S[m][3] = fmaf(q1.w, ps[m], S[m][3]);
        const float tn = fmaf(pc[m], stc[m], -ps[m] * sts[m]);
        ps[m] = fmaf(pc[m], sts[m], ps[m] * stc[m]);
        pc[m] = tn;
      }
    }
    const long rbase = (long)bc * 256 + yq * 32;
#pragma unroll
    for (int m = 0; m < 4; ++m) {
      const int xx = xq + 32 * m;
#pragma unroll
      for (int j = 0; j < 4; ++j) {
        const long row = rbase + rh * 4 + j;
        out[row * 256 + xx] = C[m][j] - S[m][j];
        out[row * 256 + ((256 - xx) & 255)] = C[m][j] + S[m][j];
      }
    }
    if (tid < 32) {  // column x=128: sum (-1)^w a_w
      float ae = 0.f, ao = 0.f;
#pragma unroll
      for (int k = 0; k < 16; ++k) {
        ae += tst[(2 * k) * 34 + tid].x;
        ao += tst[(2 * k + 1) * 34 + tid].x;
      }
      out[(rbase + tid) * 256 + 128] = ae - ao;
    }
  }
}

extern "C" void kernel_launch(void* const* d_in, const int* in_sizes, int n_in,
                              void* d_out, int out_size, void* d_ws, size_t ws_size,
                              hipStream_t stream) {
  const float* x = (const float*)d_in[0];
  const float* kin = (const float*)d_in[1];
  const float* rp = (const float*)d_in[2];
  float* out = (float*)d_out;
  char* ws = (char*)d_ws;

  float2* z1 = (float2*)(ws);                   // 0..16M (kA w, kB1 rw, kB2 r)
  float2* z2 = (float2*)(ws + (16ull << 20));   // 16..24M (kB2 w, kC r)
  float2* kp = (float2*)(ws + (24ull << 20));   // 24..24.5M (kP w, kC r)
  float2* g  = (float2*)(ws);                   // 0..4M (kC w, kD1 r)
  float2* U  = (float2*)(ws + (4ull << 20));    // 4..21M (kD1 w, kDE r)

  kP<<<256, 256, 0, stream>>>(kin, rp, kp);
  kA<<<2048, 256, 0, stream>>>(x, z1);
  kB1<<<1024, 256, 0, stream>>>(z1);
  kB2<<<2048, 256, 0, stream>>>(z1, z2);
  kC<<<2048, 256, 0, stream>>>(z2, kp, g);
  kD1<<<2048, 256, 0, stream>>>(g, U);
  kDE<<<2048, 256, 0, stream>>>(U, out);
}